// Round 6
// baseline (552.718 us; speedup 1.0000x reference)
//
#include <hip/hip_runtime.h>

#define NN 16
#define SS 16384
#define VV 256
#define TT ((long)NN * SS)   // 262144 tokens
#define NC 47                // total codes (padded to 48 for MFMA)

static constexpr int CB_SIZES_H[10] = {3, 5, 5, 5, 5, 3, 7, 8, 3, 3};
static constexpr int CB_OFF_H[10]   = {0, 3, 8, 13, 18, 23, 26, 33, 41, 44};

typedef float v4f    __attribute__((ext_vector_type(4)));
typedef float f32x4  __attribute__((ext_vector_type(4)));
typedef short short8 __attribute__((ext_vector_type(8)));
typedef unsigned uint2e __attribute__((ext_vector_type(2)));
typedef unsigned uint4e __attribute__((ext_vector_type(4)));

// ---------------------------------------------------------------------------
// Precompute (math verified r2-r5). su[k][n] = -2*(W1_g^T e_c)[k] split into
// bf16 hi/lo in MFMA B-fragment order; biasv; proj now stored as bf16 (RNE).
// ---------------------------------------------------------------------------
__global__ __launch_bounds__(256) void vq_pre(
    const float* __restrict__ W1, const float* __restrict__ b1,
    const float* __restrict__ W2,
    const float* __restrict__ cb0, const float* __restrict__ cb1,
    const float* __restrict__ cb2, const float* __restrict__ cb3,
    const float* __restrict__ cb4, const float* __restrict__ cb5,
    const float* __restrict__ cb6, const float* __restrict__ cb7,
    const float* __restrict__ cb8, const float* __restrict__ cb9,
    unsigned short* __restrict__ bfrag, float* __restrict__ biasv,
    unsigned short* __restrict__ projbf)
{
    const int gc = blockIdx.x;           // 0..47 (47 = zero pad column)
    const int v  = threadIdx.x;          // 0..255 = k
    const int ks = v >> 5, kl = v & 31, h = kl >> 3, j = kl & 7;

    if (gc >= NC) {                      // pad column: zeros
        const int idx = (ks * 3 + 2) * 512 + (h * 16 + 15) * 8 + j;
        bfrag[idx] = 0;
        bfrag[12288 + idx] = 0;
        return;
    }

    const float* cbs[10] = {cb0, cb1, cb2, cb3, cb4, cb5, cb6, cb7, cb8, cb9};
    int g = 0;
    #pragma unroll
    for (int gg = 1; gg < 10; gg++) if (gc >= CB_OFF_H[gg]) g = gg;
    const int c = gc - CB_OFF_H[g];
    const float* e = cbs[g] + c * 16;

    float su = 0.f, pj = 0.f;
    #pragma unroll
    for (int i = 0; i < 16; i++)
        su = fmaf(W1[(long)(16 * g + i) * VV + v], e[i], su);
    const float s2 = -2.f * su;

    const unsigned u = __builtin_bit_cast(unsigned, s2);
    const float r = s2 - __builtin_bit_cast(float, u & 0xFFFF0000u);
    unsigned t = __builtin_bit_cast(unsigned, r);
    t += 0x7FFFu + ((t >> 16) & 1u);
    const int idx = (ks * 3 + (gc >> 4)) * 512 + (h * 16 + (gc & 15)) * 8 + j;
    bfrag[idx]         = (unsigned short)(u >> 16);
    bfrag[12288 + idx] = (unsigned short)(t >> 16);

    #pragma unroll
    for (int i = 0; i < 16; i++)
        pj = fmaf(e[i], W2[(long)v * 160 + i * 10 + g], pj);
    unsigned tp = __builtin_bit_cast(unsigned, pj);
    tp += 0x7FFFu + ((tp >> 16) & 1u);          // RNE to bf16
    projbf[gc * VV + v] = (unsigned short)(tp >> 16);

    if (v == 0) {
        float b = 0.f;
        #pragma unroll
        for (int i = 0; i < 16; i++)
            b += e[i] * (e[i] - 2.f * b1[16 * g + i]);
        biasv[gc] = b;
    }
}

// ---------------------------------------------------------------------------
static __device__ __forceinline__ void cvt_hi_lo(
    const float4 f0, const float4 f1, short8& ah, short8& al)
{
    const float f[8] = {f0.x, f0.y, f0.z, f0.w, f1.x, f1.y, f1.z, f1.w};
    uint4e H, L;
    #pragma unroll
    for (int p = 0; p < 4; p++) {
        const unsigned u0 = __builtin_bit_cast(unsigned, f[2 * p]);
        const unsigned u1 = __builtin_bit_cast(unsigned, f[2 * p + 1]);
        H[p] = (u0 >> 16) | (u1 & 0xFFFF0000u);
        const float r0 = f[2 * p]     - __builtin_bit_cast(float, u0 & 0xFFFF0000u);
        const float r1 = f[2 * p + 1] - __builtin_bit_cast(float, u1 & 0xFFFF0000u);
        unsigned t0 = __builtin_bit_cast(unsigned, r0);
        unsigned t1 = __builtin_bit_cast(unsigned, r1);
        t0 += 0x7FFFu + ((t0 >> 16) & 1u);
        t1 += 0x7FFFu + ((t1 >> 16) & 1u);
        L[p] = (t0 >> 16) | (t1 & 0xFFFF0000u);
    }
    ah = __builtin_bit_cast(short8, H);
    al = __builtin_bit_cast(short8, L);
}

static __device__ __forceinline__ unsigned argmin_pack(const float* acc) {
    unsigned p = 0;
    #pragma unroll
    for (int g = 0; g < 10; g++) {
        const int off = CB_OFF_H[g];
        const int k = CB_SIZES_H[g];
        float best = acc[off];
        int bi = 0;
        #pragma unroll
        for (int c = 1; c < 8; c++) {
            if (c < k) {
                const float vv = acc[off + c];
                if (vv < best) { best = vv; bi = c; }  // strict <: np first-min
            }
        }
        p |= (unsigned)bi << (3 * g);
    }
    return p;
}

// ---------------------------------------------------------------------------
// Fused kernel. Block = 256 threads / 256 tokens. Occupancy-first design:
// LDS union is only 24064 B = max(scan [4][16][49] fp32, proj bf16 NC*256)
// -> 5 blocks/CU (20 waves/CU) with __launch_bounds__(256,5), VGPR <= 102.
// Phase 1: A from global (per-lane gather, r2-verified), B from global
//   (block-uniform 48 KB, L2-resident) -> NO LDS, NO barriers in the K-loop.
// Phase 1b: per-m-tile scan through per-wave [16][49] slab (in-order DS ops
//   within a wave -> no barriers).
// Phase 2: proj as bf16 in LDS (ds_read_b64/code), pk in registers.
// ---------------------------------------------------------------------------
__global__ __launch_bounds__(256, 5) void vq_fused(
    const float* __restrict__ x, const unsigned short* __restrict__ bfrag,
    const float* __restrict__ biasv, const unsigned short* __restrict__ projbf,
    const float* __restrict__ b2,
    float* __restrict__ out0, float* __restrict__ out1,
    float* __restrict__ out2)
{
    __shared__ __align__(16) char smem[24064];              // union
    float (*sc)[16][49] = (float (*)[16][49])smem;          // scan slabs
    unsigned short* plb = (unsigned short*)smem;            // phase2 proj bf16

    const int tid  = threadIdx.x;
    const int w    = tid >> 6;
    const int lane = tid & 63;
    const int h    = lane >> 4;          // A: k-group ; C: row-group
    const int nl   = lane & 15;          // A: row     ; B/C: col
    const long t0  = (long)blockIdx.x * 256;
    const long tw  = t0 + (long)w * 64;  // this wave's first token

    f32x4 acc[4][3];
    #pragma unroll
    for (int m = 0; m < 4; m++)
        #pragma unroll
        for (int nt = 0; nt < 3; nt++)
            acc[m][nt] = (f32x4){0.f, 0.f, 0.f, 0.f};

    const float* ab = x + (tw + nl) * VV + h * 8;    // A fragment base
    const unsigned short* bh_ptr = bfrag + lane * 8;
    const unsigned short* bl_ptr = bfrag + 12288 + lane * 8;

    #pragma unroll
    for (int ks = 0; ks < 8; ks++) {
        short8 bh[3], bl[3];
        #pragma unroll
        for (int nt = 0; nt < 3; nt++) {
            bh[nt] = *(const short8*)(bh_ptr + (ks * 3 + nt) * 512);
            bl[nt] = *(const short8*)(bl_ptr + (ks * 3 + nt) * 512);
        }
        #pragma unroll
        for (int m = 0; m < 4; m++) {
            const float* base = ab + m * 16 * VV + ks * 32;
            const float4 f0 = *(const float4*)(base);
            const float4 f1 = *(const float4*)(base + 4);
            short8 ah, al;
            cvt_hi_lo(f0, f1, ah, al);
            #pragma unroll
            for (int nt = 0; nt < 3; nt++) {
                acc[m][nt] = __builtin_amdgcn_mfma_f32_16x16x32_bf16(ah, bh[nt], acc[m][nt], 0, 0, 0);
                acc[m][nt] = __builtin_amdgcn_mfma_f32_16x16x32_bf16(ah, bl[nt], acc[m][nt], 0, 0, 0);
                acc[m][nt] = __builtin_amdgcn_mfma_f32_16x16x32_bf16(al, bh[nt], acc[m][nt], 0, 0, 0);
            }
        }
    }

    // ---- scan per m-tile through per-wave [16][49] slab (no barriers).
    // C layout: col = lane&15, row = (lane>>4)*4 + reg -> token m*16+4h+r.
    float arr[NC];
    #pragma unroll
    for (int m = 0; m < 4; m++) {
        #pragma unroll
        for (int nt = 0; nt < 3; nt++)
            #pragma unroll
            for (int r = 0; r < 4; r++)
                sc[w][h * 4 + r][nt * 16 + nl] = acc[m][nt][r];
        // in-wave DS ordering: write(m) -> read(m) -> write(m+1) is safe
        if ((lane >> 4) == m) {
            #pragma unroll
            for (int c = 0; c < NC; c++)
                arr[c] = sc[w][lane & 15][c] + biasv[c];
        }
    }
    const unsigned p = argmin_pack(arr);      // token tw + lane

    // ---- phase 2: proj (bf16) into LDS, stream outputs ----
    __syncthreads();                          // all scans done before overwrite
    for (int i = tid; i < (NC * VV) / 8; i += 256)
        ((uint4e*)smem)[i] = ((const uint4e*)projbf)[i];
    __syncthreads();

    const v4f b2v = ((const v4f*)b2)[lane];

    // xv prefetch depth 2
    v4f xv0 = ((const v4f*)(x + tw * VV))[lane];
    v4f xv1 = ((const v4f*)(x + (tw + 1) * VV))[lane];

    #pragma unroll 2
    for (int tok = 0; tok < 64; tok++) {
        const v4f xv = xv0;
        xv0 = xv1;
        if (tok < 62)
            xv1 = ((const v4f*)(x + (tw + tok + 2) * VV))[lane];

        const unsigned pkt = (unsigned)__shfl((int)p, tok);
        v4f o = b2v;
        #pragma unroll
        for (int g = 0; g < 10; g++) {
            const int cc = CB_OFF_H[g] + (int)((pkt >> (3 * g)) & 7u);
            const uint2e u = *(const uint2e*)(plb + cc * VV + lane * 4);
            v4f pv;
            pv.x = __builtin_bit_cast(float, u.x << 16);
            pv.y = __builtin_bit_cast(float, u.x & 0xFFFF0000u);
            pv.z = __builtin_bit_cast(float, u.y << 16);
            pv.w = __builtin_bit_cast(float, u.y & 0xFFFF0000u);
            o += pv;
        }
        const long t = tw + tok;
        v4f s = (o - xv) + xv;   // match reference rounding for out0
        __builtin_nontemporal_store(s, (v4f*)(out0 + t * VV) + lane);

        const v4f d = xv - o;
        float pr = d.x * d.x + d.y * d.y + d.z * d.z + d.w * d.w;
        #pragma unroll
        for (int off = 32; off > 0; off >>= 1)
            pr += __shfl_xor(pr, off);
        if (lane == 0)  out1[t] = pr;
        if (lane == 32) out2[t] = pr;
    }
}

// ---------------------------------------------------------------------------
extern "C" void kernel_launch(void* const* d_in, const int* in_sizes, int n_in,
                              void* d_out, int out_size, void* d_ws, size_t ws_size,
                              hipStream_t stream) {
    const float* x0 = (const float*)d_in[0];
    const float* W1 = (const float*)d_in[1];
    const float* b1 = (const float*)d_in[2];
    const float* W2 = (const float*)d_in[3];
    const float* b2 = (const float*)d_in[4];
    const float* cb[10];
    for (int i = 0; i < 10; i++) cb[i] = (const float*)d_in[5 + i];

    float* ws = (float*)d_ws;
    unsigned short* bfrag = (unsigned short*)ws;        // 24576 ushorts = 49152 B
    float* biasv = ws + 12288;                          // 47 floats (+pad)
    unsigned short* projbf = (unsigned short*)(ws + 12352);  // 12032 ushorts

    float* out0 = (float*)d_out;
    float* out1 = out0 + (long)NN * SS * VV;  // 67108864
    float* out2 = out1 + (long)NN * SS;       // +262144

    vq_pre<<<NC + 1, 256, 0, stream>>>(W1, b1, W2,
        cb[0], cb[1], cb[2], cb[3], cb[4], cb[5], cb[6], cb[7], cb[8], cb[9],
        bfrag, biasv, projbf);

    vq_fused<<<(int)(TT / 256), 256, 0, stream>>>(
        x0, bfrag, biasv, projbf, b2, out0, out1, out2);
}